// Round 1
// baseline (1042.776 us; speedup 1.0000x reference)
//
#include <hip/hip_runtime.h>
#include <cstdint>
#include <cstddef>

// GRU critic, fully fused: x = relu(S@W1^T+b1); gx = x@Wih^T+bih;
// gh = h@Whh^T+bhh; gates; h' = (1-z)*n + z*h; out = h_T@Wout^T+bout.
// One block = 16 batch rows, full T=512 scan. bf16 MFMA, fp32 acc/state.

#define T_STEPS 512
#define SD 128
#define HID 64
#define NB 16

typedef __attribute__((ext_vector_type(8))) short short8;
typedef __attribute__((ext_vector_type(4))) float floatx4;

__device__ __forceinline__ unsigned short f2bf(float f) {
  union { float f; unsigned u; } v; v.f = f;
  return (unsigned short)((v.u + 0x7FFFu + ((v.u >> 16) & 1u)) >> 16);
}

__device__ __forceinline__ short8 pack8(float4 a, float4 b) {
  short8 v;
  v[0] = (short)f2bf(a.x); v[1] = (short)f2bf(a.y);
  v[2] = (short)f2bf(a.z); v[3] = (short)f2bf(a.w);
  v[4] = (short)f2bf(b.x); v[5] = (short)f2bf(b.y);
  v[6] = (short)f2bf(b.z); v[7] = (short)f2bf(b.w);
  return v;
}

// A-packed LDS layout for a [16 rows][K] bf16 tile, K in chunks of 32:
// element (m,k): c=k>>5, qk=(k>>3)&3, j=k&7 -> idx = ((c*64)+(qk*16+m))*8 + j
// => lane L of a wave reads its A-fragment for chunk c as one b128 at
//    (c*64 + L)*8, fully lane-contiguous (no pathological conflicts).

__global__ __launch_bounds__(256) void gru_fused(
    const float* __restrict__ S,     // [B, T, 128]
    const float* __restrict__ W1,    // [64, 128]
    const float* __restrict__ b1,    // [64]
    const float* __restrict__ Wih,   // [192, 64]
    const float* __restrict__ Whh,   // [192, 64]
    const float* __restrict__ bih,   // [192]
    const float* __restrict__ bhh,   // [192]
    const float* __restrict__ Wout,  // [1, 64]
    const float* __restrict__ bout,  // [1]
    float* __restrict__ out)         // [B]
{
  __shared__ __attribute__((aligned(16))) short sS[4 * 64 * 8];   // S tile, K=128
  __shared__ __attribute__((aligned(16))) short sX[2 * 64 * 8];   // X tile, K=64
  __shared__ __attribute__((aligned(16))) short sHb[2 * 64 * 8];  // h bf16, K=64
  __shared__ float sHf[NB * 68];                                  // h fp32, pad 68

  const int td = threadIdx.x;
  const int w = td >> 6;        // wave 0..3
  const int lane = td & 63;
  const int l16 = lane & 15;
  const int quad = lane >> 4;
  const int r0 = blockIdx.x * NB;

  // ---- resident weight B-fragments (n = l16 within tile, k = quad*8+j) ----
  short8 w1f[4], wihf[3][2], whhf[3][2];
  {
    const float* p = W1 + (16 * w + l16) * SD + quad * 8;
#pragma unroll
    for (int c = 0; c < 4; ++c) {
      short8 f;
#pragma unroll
      for (int j = 0; j < 8; ++j) f[j] = (short)f2bf(p[32 * c + j]);
      w1f[c] = f;
    }
  }
#pragma unroll
  for (int i = 0; i < 3; ++i) {
    const int n = 16 * (w + 4 * i) + l16;
#pragma unroll
    for (int c = 0; c < 2; ++c) {
      const float* q  = Wih + n * HID + 32 * c + quad * 8;
      const float* q2 = Whh + n * HID + 32 * c + quad * 8;
      short8 f, g;
#pragma unroll
      for (int j = 0; j < 8; ++j) {
        f[j] = (short)f2bf(q[j]);
        g[j] = (short)f2bf(q2[j]);
      }
      wihf[i][c] = f;
      whhf[i][c] = g;
    }
  }
  const int col = 16 * w + l16;  // h-unit column this lane owns in gate math
  const float b1c = b1[col];
  float bihc[3], bhhc[3];
#pragma unroll
  for (int i = 0; i < 3; ++i) {
    bihc[i] = bih[col + 64 * i];
    bhhc[i] = bhh[col + 64 * i];
  }

  // ---- staging: thread -> (row sm, 8 consecutive k at k0) ----
  const int sm = td & 15;
  const int k0 = (td >> 4) * 8;
  const float* sp = S + ((size_t)(r0 + sm) * T_STEPS) * SD + k0;
  short* sSslot = &sS[(((k0 >> 5) * 64) + ((k0 >> 3) & 3) * 16 + sm) * 8];

  // zero h state
  for (int i = td; i < 2 * 64 * 8; i += 256) sHb[i] = 0;
  for (int i = td; i < NB * 68; i += 256) sHf[i] = 0.0f;

  // prologue: stage S_0, prefetch S_1
  float4 pf0 = *(const float4*)(sp);
  float4 pf1 = *(const float4*)(sp + 4);
  *(short8*)sSslot = pack8(pf0, pf1);
  pf0 = *(const float4*)(sp + 1 * SD);
  pf1 = *(const float4*)(sp + 1 * SD + 4);
  __syncthreads();

  const int mbase = quad * 4;
  const int pc = col >> 5, pqk = (col >> 3) & 3, pj = col & 7;
  short* xWp  = &sX [((pc * 64) + pqk * 16 + mbase) * 8 + pj];
  short* hbWp = &sHb[((pc * 64) + pqk * 16 + mbase) * 8 + pj];
  float* hfp  = &sHf[mbase * 68 + col];

  for (int t = 0; t < T_STEPS; ++t) {
    // ---- phase C: GH = h@Whh^T + bhh ; Xacc = S@W1^T + b1 ----
    short8 hf0 = *(const short8*)&sHb[(0 * 64 + lane) * 8];
    short8 hf1 = *(const short8*)&sHb[(1 * 64 + lane) * 8];
    short8 sf[4];
#pragma unroll
    for (int c = 0; c < 4; ++c) sf[c] = *(const short8*)&sS[(c * 64 + lane) * 8];

    floatx4 accGH[3];
#pragma unroll
    for (int i = 0; i < 3; ++i) {
      floatx4 a = { bhhc[i], bhhc[i], bhhc[i], bhhc[i] };
      a = __builtin_amdgcn_mfma_f32_16x16x32_bf16(hf0, whhf[i][0], a, 0, 0, 0);
      a = __builtin_amdgcn_mfma_f32_16x16x32_bf16(hf1, whhf[i][1], a, 0, 0, 0);
      accGH[i] = a;
    }
    floatx4 accX = { b1c, b1c, b1c, b1c };
#pragma unroll
    for (int c = 0; c < 4; ++c)
      accX = __builtin_amdgcn_mfma_f32_16x16x32_bf16(sf[c], w1f[c], accX, 0, 0, 0);

    // relu + write X (A-packed, element (mbase+r, col))
#pragma unroll
    for (int r = 0; r < 4; ++r) {
      float xv = accX[r];
      xv = xv > 0.0f ? xv : 0.0f;
      xWp[r * 8] = (short)f2bf(xv);
    }
    __syncthreads();  // b2: sX ready; sS/sHb reads done

    // ---- phase A': stage S_{t+1}, prefetch S_{t+2} ----
    if (t + 1 < T_STEPS) *(short8*)sSslot = pack8(pf0, pf1);
    {
      const int tn = (t + 2 < T_STEPS) ? t + 2 : T_STEPS - 1;
      pf0 = *(const float4*)(sp + (size_t)tn * SD);
      pf1 = *(const float4*)(sp + (size_t)tn * SD + 4);
    }

    // ---- phase E: GX = x@Wih^T + bih ; gates; h update ----
    short8 xf0 = *(const short8*)&sX[(0 * 64 + lane) * 8];
    short8 xf1 = *(const short8*)&sX[(1 * 64 + lane) * 8];
    floatx4 accGX[3];
#pragma unroll
    for (int i = 0; i < 3; ++i) {
      floatx4 a = { bihc[i], bihc[i], bihc[i], bihc[i] };
      a = __builtin_amdgcn_mfma_f32_16x16x32_bf16(xf0, wihf[i][0], a, 0, 0, 0);
      a = __builtin_amdgcn_mfma_f32_16x16x32_bf16(xf1, wihf[i][1], a, 0, 0, 0);
      accGX[i] = a;
    }
#pragma unroll
    for (int r = 0; r < 4; ++r) {
      float gr = accGX[0][r] + accGH[0][r];
      float gz = accGX[1][r] + accGH[1][r];
      float rg = 1.0f / (1.0f + __expf(-gr));
      float zg = 1.0f / (1.0f + __expf(-gz));
      float gn = accGX[2][r] + rg * accGH[2][r];
      float ng = 2.0f / (1.0f + __expf(-2.0f * gn)) - 1.0f;
      float ho = hfp[r * 68];
      float hn = zg * (ho - ng) + ng;
      hfp[r * 68] = hn;
      hbWp[r * 8] = (short)f2bf(hn);
    }
    __syncthreads();  // b3: h_{t+1} + S_{t+1} visible
  }

  // ---- epilogue: value = h_T @ Wout^T + bout ----
  if (td < NB) {
    float acc = bout[0];
#pragma unroll
    for (int c = 0; c < HID; ++c) acc += sHf[td * 68 + c] * Wout[c];
    out[r0 + td] = acc;
  }
}

extern "C" void kernel_launch(void* const* d_in, const int* in_sizes, int n_in,
                              void* d_out, int out_size, void* d_ws, size_t ws_size,
                              hipStream_t stream) {
  const float* S    = (const float*)d_in[0];
  const float* W1   = (const float*)d_in[1];
  const float* b1   = (const float*)d_in[2];
  const float* Wih  = (const float*)d_in[3];
  const float* Whh  = (const float*)d_in[4];
  const float* bih  = (const float*)d_in[5];
  const float* bhh  = (const float*)d_in[6];
  const float* Wout = (const float*)d_in[7];
  const float* bout = (const float*)d_in[8];
  float* out = (float*)d_out;

  const int B = in_sizes[0] / (T_STEPS * SD);  // 2048
  dim3 grid(B / NB);                           // 128 blocks
  gru_fused<<<grid, 256, 0, stream>>>(S, W1, b1, Wih, Whh, bih, bhh, Wout, bout, out);
}

// Round 2
// 913.112 us; speedup vs baseline: 1.1420x; 1.1420x over previous
//
#include <hip/hip_runtime.h>
#include <cstdint>
#include <cstddef>

// GRU critic, producer/consumer fused kernel.
// Block = 512 threads = 8 waves, one 16-row batch group, full T=512 scan.
// Waves 0-3 (consumers): recurrence only: GH = h@Whh^T + bhh -> gates -> h'.
//   h fp32 master lives in registers (C-layout is lane-stationary across steps);
//   only the bf16 A-packed copy round-trips LDS for the next step's MFMA.
// Waves 4-7 (producers): stage S (global->LDS bf16), X = relu(S@W1^T + b1),
//   GX = X@Wih^T + bih, written 1-2 steps ahead into double-buffered rings.
// Exactly ONE __syncthreads per step (vs 2 in round 1); everything
// h-independent is off the critical path.

#define T_STEPS 512
#define SD 128
#define HID 64
#define NB 16

typedef __attribute__((ext_vector_type(8))) short short8;
typedef __attribute__((ext_vector_type(4))) float floatx4;

__device__ __forceinline__ unsigned short f2bf(float f) {
  union { float f; unsigned u; } v; v.f = f;
  return (unsigned short)((v.u + 0x7FFFu + ((v.u >> 16) & 1u)) >> 16);
}

__device__ __forceinline__ short8 pack8(float4 a, float4 b) {
  short8 v;
  v[0] = (short)f2bf(a.x); v[1] = (short)f2bf(a.y);
  v[2] = (short)f2bf(a.z); v[3] = (short)f2bf(a.w);
  v[4] = (short)f2bf(b.x); v[5] = (short)f2bf(b.y);
  v[6] = (short)f2bf(b.z); v[7] = (short)f2bf(b.w);
  return v;
}

__device__ __forceinline__ float sigm(float x) {
  return __builtin_amdgcn_rcpf(1.0f + __expf(-x));
}

// A-packed LDS layout for a [16 rows][K] bf16 tile:
// (m,k) -> ((k>>5)*64 + ((k>>3)&3)*16 + m)*8 + (k&7); lane L reads chunk c
// as one ds_read_b128 at (c*64+L)*8 (lane-contiguous, conflict-free).
__device__ __forceinline__ int apack(int m, int k) {
  return ((k >> 5) * 64 + ((k >> 3) & 3) * 16 + m) * 8 + (k & 7);
}

__global__ __launch_bounds__(512, 2) void gru_pc(
    const float* __restrict__ S,     // [B, T, 128]
    const float* __restrict__ W1,    // [64, 128]
    const float* __restrict__ b1,    // [64]
    const float* __restrict__ Wih,   // [192, 64]
    const float* __restrict__ Whh,   // [192, 64]
    const float* __restrict__ bih,   // [192]
    const float* __restrict__ bhh,   // [192]
    const float* __restrict__ Wout,  // [1, 64]
    const float* __restrict__ bout,  // [1]
    float* __restrict__ out)         // [B]
{
  __shared__ __attribute__((aligned(16))) short sS[2][4 * 64 * 8];   // S rings (K=128)
  __shared__ __attribute__((aligned(16))) short sX[2][2 * 64 * 8];   // X rings (K=64)
  __shared__ __attribute__((aligned(16))) short sHb[2][2 * 64 * 8];  // h bf16 rings
  __shared__ __attribute__((aligned(16))) float gGX[2][3][4][64 * 4];// GX fp32 rings
  __shared__ float sOut[NB];

  const int td = threadIdx.x;
  const int w = td >> 6;        // wave 0..7
  const int lane = td & 63;
  const int l16 = lane & 15;
  const int quad = lane >> 4;
  const int r0 = blockIdx.x * NB;
  const bool consumer = (w < 4);

  // ------------------- consumer state -------------------
  short8 whhf[3][2];
  float bhhc[3];
  float ho[4] = {0.0f, 0.0f, 0.0f, 0.0f};
  const int ccol = 16 * (w & 3) + l16;
  short* hwBase[2];
  hwBase[0] = &sHb[0][apack(quad * 4, ccol)];
  hwBase[1] = &sHb[1][apack(quad * 4, ccol)];

  // ------------------- producer state -------------------
  const int wp = w & 3;
  short8 w1f[4], wihf[3][2];
  float b1c = 0.0f, bihc[3];
  const int pt = td & 255;
  const int sm = pt & 15;
  const int k0 = (pt >> 4) * 8;
  const float* sp = S + ((size_t)(r0 + sm) * T_STEPS) * SD + k0;
  const int sSoff = apack(sm, k0);
  const int pcol = 16 * wp + l16;
  short* xwBase[2];
  xwBase[0] = &sX[0][apack(quad * 4, pcol)];
  xwBase[1] = &sX[1][apack(quad * 4, pcol)];
  float4 pf0, pf1;

  if (consumer) {
#pragma unroll
    for (int i = 0; i < 3; ++i) {
      const int n = 16 * (wp + 4 * i) + l16;
#pragma unroll
      for (int c = 0; c < 2; ++c) {
        const float* q = Whh + n * HID + 32 * c + quad * 8;
        short8 g;
#pragma unroll
        for (int j = 0; j < 8; ++j) g[j] = (short)f2bf(q[j]);
        whhf[i][c] = g;
      }
      bhhc[i] = bhh[ccol + 64 * i];
    }
    // zero initial h (bf16 ring 0) and sOut
    for (int i = td; i < 2 * 64 * 8; i += 256) sHb[0][i] = 0;
    if (td < NB) sOut[td] = 0.0f;
  } else {
    {
      const float* p = W1 + pcol * SD + quad * 8;
#pragma unroll
      for (int c = 0; c < 4; ++c) {
        short8 f;
#pragma unroll
        for (int j = 0; j < 8; ++j) f[j] = (short)f2bf(p[32 * c + j]);
        w1f[c] = f;
      }
      b1c = b1[pcol];
    }
#pragma unroll
    for (int i = 0; i < 3; ++i) {
      const int n = 16 * (wp + 4 * i) + l16;
#pragma unroll
      for (int c = 0; c < 2; ++c) {
        const float* q = Wih + n * HID + 32 * c + quad * 8;
        short8 f;
#pragma unroll
        for (int j = 0; j < 8; ++j) f[j] = (short)f2bf(q[j]);
        wihf[i][c] = f;
      }
      bihc[i] = bih[pcol + 64 * i];
    }
    // warmup W1: stage S(0), S(1); prefetch S(2)
    float4 a0 = *(const float4*)(sp);
    float4 a1 = *(const float4*)(sp + 4);
    float4 c0 = *(const float4*)(sp + SD);
    float4 c1 = *(const float4*)(sp + SD + 4);
    *(short8*)&sS[0][sSoff] = pack8(a0, a1);
    *(short8*)&sS[1][sSoff] = pack8(c0, c1);
    pf0 = *(const float4*)(sp + 2 * SD);
    pf1 = *(const float4*)(sp + 2 * SD + 4);
  }
  __syncthreads();  // A

  if (!consumer) {
    // warmup W2: X(0) -> sX[0], X(1) -> sX[1]
#pragma unroll
    for (int s = 0; s < 2; ++s) {
      short8 sf[4];
#pragma unroll
      for (int c = 0; c < 4; ++c) sf[c] = *(const short8*)&sS[s][(c * 64 + lane) * 8];
      floatx4 ax = {b1c, b1c, b1c, b1c};
      floatx4 ax2 = {0.0f, 0.0f, 0.0f, 0.0f};
      ax  = __builtin_amdgcn_mfma_f32_16x16x32_bf16(sf[0], w1f[0], ax, 0, 0, 0);
      ax  = __builtin_amdgcn_mfma_f32_16x16x32_bf16(sf[1], w1f[1], ax, 0, 0, 0);
      ax2 = __builtin_amdgcn_mfma_f32_16x16x32_bf16(sf[2], w1f[2], ax2, 0, 0, 0);
      ax2 = __builtin_amdgcn_mfma_f32_16x16x32_bf16(sf[3], w1f[3], ax2, 0, 0, 0);
#pragma unroll
      for (int r = 0; r < 4; ++r) {
        float xv = ax[r] + ax2[r];
        xwBase[s][r * 8] = (short)f2bf(xv > 0.0f ? xv : 0.0f);
      }
    }
  }
  __syncthreads();  // B

  if (!consumer) {
    // warmup W3: GX(0) -> gGX[0]; stage S(2) -> sS[0]; prefetch S(3)
    short8 xf0 = *(const short8*)&sX[0][(0 * 64 + lane) * 8];
    short8 xf1 = *(const short8*)&sX[0][(1 * 64 + lane) * 8];
#pragma unroll
    for (int i = 0; i < 3; ++i) {
      floatx4 a = {bihc[i], bihc[i], bihc[i], bihc[i]};
      a = __builtin_amdgcn_mfma_f32_16x16x32_bf16(xf0, wihf[i][0], a, 0, 0, 0);
      a = __builtin_amdgcn_mfma_f32_16x16x32_bf16(xf1, wihf[i][1], a, 0, 0, 0);
      *(floatx4*)&gGX[0][i][wp][lane * 4] = a;
    }
    *(short8*)&sS[0][sSoff] = pack8(pf0, pf1);
    pf0 = *(const float4*)(sp + (size_t)3 * SD);
    pf1 = *(const float4*)(sp + (size_t)3 * SD + 4);
  }
  __syncthreads();  // C

  for (int t = 0; t < T_STEPS; ++t) {
    if (consumer) {
      const int pH = t & 1;
      // GX reads first (independent of h)
      floatx4 gx0 = *(const floatx4*)&gGX[pH][0][wp][lane * 4];
      floatx4 gx1 = *(const floatx4*)&gGX[pH][1][wp][lane * 4];
      floatx4 gx2 = *(const floatx4*)&gGX[pH][2][wp][lane * 4];
      short8 hf0 = *(const short8*)&sHb[pH][(0 * 64 + lane) * 8];
      short8 hf1 = *(const short8*)&sHb[pH][(1 * 64 + lane) * 8];
      floatx4 g0 = {bhhc[0], bhhc[0], bhhc[0], bhhc[0]};
      floatx4 g1 = {bhhc[1], bhhc[1], bhhc[1], bhhc[1]};
      floatx4 g2 = {bhhc[2], bhhc[2], bhhc[2], bhhc[2]};
      g0 = __builtin_amdgcn_mfma_f32_16x16x32_bf16(hf0, whhf[0][0], g0, 0, 0, 0);
      g1 = __builtin_amdgcn_mfma_f32_16x16x32_bf16(hf0, whhf[1][0], g1, 0, 0, 0);
      g2 = __builtin_amdgcn_mfma_f32_16x16x32_bf16(hf0, whhf[2][0], g2, 0, 0, 0);
      g0 = __builtin_amdgcn_mfma_f32_16x16x32_bf16(hf1, whhf[0][1], g0, 0, 0, 0);
      g1 = __builtin_amdgcn_mfma_f32_16x16x32_bf16(hf1, whhf[1][1], g1, 0, 0, 0);
      g2 = __builtin_amdgcn_mfma_f32_16x16x32_bf16(hf1, whhf[2][1], g2, 0, 0, 0);
      short* hw = hwBase[1 - pH];
#pragma unroll
      for (int r = 0; r < 4; ++r) {
        float rg = sigm(gx0[r] + g0[r]);
        float zg = sigm(gx1[r] + g1[r]);
        float gn = gx2[r] + rg * g2[r];
        float e = __expf(2.0f * gn);
        float ng = 1.0f - 2.0f * __builtin_amdgcn_rcpf(e + 1.0f);
        float hn = zg * (ho[r] - ng) + ng;
        ho[r] = hn;
        hw[r * 8] = (short)f2bf(hn);
      }
    } else {
      const int pGX = (t + 1) & 1;  // write GX(t+1)
      const int pXr = (t + 1) & 1;  // read  X(t+1)
      const int pXw = t & 1;        // write X(t+2)
      const int pSr = t & 1;        // read  S(t+2)
      const int pSw = (t + 1) & 1;  // stage S(t+3)

      short8 xf0 = *(const short8*)&sX[pXr][(0 * 64 + lane) * 8];
      short8 xf1 = *(const short8*)&sX[pXr][(1 * 64 + lane) * 8];
      short8 sf[4];
#pragma unroll
      for (int c = 0; c < 4; ++c) sf[c] = *(const short8*)&sS[pSr][(c * 64 + lane) * 8];

#pragma unroll
      for (int i = 0; i < 3; ++i) {
        floatx4 a = {bihc[i], bihc[i], bihc[i], bihc[i]};
        a = __builtin_amdgcn_mfma_f32_16x16x32_bf16(xf0, wihf[i][0], a, 0, 0, 0);
        a = __builtin_amdgcn_mfma_f32_16x16x32_bf16(xf1, wihf[i][1], a, 0, 0, 0);
        *(floatx4*)&gGX[pGX][i][wp][lane * 4] = a;
      }
      floatx4 ax = {b1c, b1c, b1c, b1c};
      floatx4 ax2 = {0.0f, 0.0f, 0.0f, 0.0f};
      ax  = __builtin_amdgcn_mfma_f32_16x16x32_bf16(sf[0], w1f[0], ax, 0, 0, 0);
      ax  = __builtin_amdgcn_mfma_f32_16x16x32_bf16(sf[1], w1f[1], ax, 0, 0, 0);
      ax2 = __builtin_amdgcn_mfma_f32_16x16x32_bf16(sf[2], w1f[2], ax2, 0, 0, 0);
      ax2 = __builtin_amdgcn_mfma_f32_16x16x32_bf16(sf[3], w1f[3], ax2, 0, 0, 0);
      short* xw = xwBase[pXw];
#pragma unroll
      for (int r = 0; r < 4; ++r) {
        float xv = ax[r] + ax2[r];
        xw[r * 8] = (short)f2bf(xv > 0.0f ? xv : 0.0f);
      }
      *(short8*)&sS[pSw][sSoff] = pack8(pf0, pf1);
      int tn = t + 4; if (tn > T_STEPS - 1) tn = T_STEPS - 1;
      pf0 = *(const float4*)(sp + (size_t)tn * SD);
      pf1 = *(const float4*)(sp + (size_t)tn * SD + 4);
    }
    __syncthreads();
  }

  // epilogue: value = h_T @ Wout^T + bout
  if (consumer) {
#pragma unroll
    for (int r = 0; r < 4; ++r)
      atomicAdd(&sOut[quad * 4 + r], ho[r] * Wout[ccol]);
  }
  __syncthreads();
  if (td < NB) out[r0 + td] = sOut[td] + bout[0];
}

extern "C" void kernel_launch(void* const* d_in, const int* in_sizes, int n_in,
                              void* d_out, int out_size, void* d_ws, size_t ws_size,
                              hipStream_t stream) {
  const float* S    = (const float*)d_in[0];
  const float* W1   = (const float*)d_in[1];
  const float* b1   = (const float*)d_in[2];
  const float* Wih  = (const float*)d_in[3];
  const float* Whh  = (const float*)d_in[4];
  const float* bih  = (const float*)d_in[5];
  const float* bhh  = (const float*)d_in[6];
  const float* Wout = (const float*)d_in[7];
  const float* bout = (const float*)d_in[8];
  float* out = (float*)d_out;

  const int B = in_sizes[0] / (T_STEPS * SD);  // 2048
  dim3 grid(B / NB);                           // 128 blocks
  gru_pc<<<grid, 512, 0, stream>>>(S, W1, b1, Wih, Whh, bih, bhh, Wout, bout, out);
}